// Round 3
// baseline (89.456 us; speedup 1.0000x reference)
//
#include <hip/hip_runtime.h>
#include <math.h>

static constexpr int S_LEN = 2048;
static constexpr int KMIX  = 20;
static constexpr int NROWS = 256 * 2048;            // B*S
static constexpr int BLOCK = 512;                   // 8 waves = 16 half-waves = 16 rows/sweep
static constexpr int ROWS_PER_BLOCK = 256;
static constexpr int NBLK  = NROWS / ROWS_PER_BLOCK; // 2048
static constexpr int SWEEPS = ROWS_PER_BLOCK / (BLOCK / 32); // 16
static constexpr float SIGMA_MIN_F = 0.01f;
static constexpr float LOG_2PI_F   = 1.8378770664093453f;

__global__ __launch_bounds__(BLOCK) void sketch_loss_kernel(
    const float* __restrict__ xs,
    const float* __restrict__ logits,
    const float* __restrict__ mus,
    const float* __restrict__ sxp,
    const float* __restrict__ syp,
    const float* __restrict__ sxyp,
    const float* __restrict__ pen,
    float* __restrict__ partials)
{
    const int j   = threadIdx.x & 31;            // component lane within half-wave
    const int hw  = threadIdx.x >> 5;            // half-wave id 0..15 -> row within sweep
    const int jj  = (j < KMIX) ? j : (KMIX - 1); // clamp to stay in-row (no OOB)
    const bool act = (j < KMIX);
    const int base = blockIdx.x * ROWS_PER_BLOCK;

    float accp = 0.0f, acce = 0.0f;

    #pragma unroll 2
    for (int i = 0; i < SWEEPS; ++i) {
        const int r = base + i * (BLOCK / 32) + hw;

        // ---- coalesced per-component loads: 20 lanes cover 80 contiguous bytes ----
        const int idx = r * KMIX + jj;
        const float lv_r = logits[idx];
        const float sxv  = sxp[idx];
        const float syv  = syp[idx];
        const float swv  = sxyp[idx];
        const float2 mu  = *(const float2*)(mus + 2 * (size_t)idx);

        // ---- per-row scalars (same address across half-wave -> broadcast) ----
        const float* xr = xs + (size_t)r * 5;
        const float x0 = xr[0], x1 = xr[1];
        const float pt0 = xr[2], pt1 = xr[3], pt2 = xr[4];
        const int s = r & (S_LEN - 1);
        const int rn = (s == S_LEN - 1) ? (r - (S_LEN - 1)) : (r + 1);
        const float* xnr = xs + (size_t)rn * 5;
        const float rel0 = xnr[0] - x0;
        const float rel1 = xnr[1] - x1;
        const float* pr = pen + (size_t)r * 3;
        const float q0 = pr[0], q1 = pr[1], q2 = pr[2];

        // ---- per-component math (one component per lane) ----
        const float sx  = fmaxf(sxv, SIGMA_MIN_F);
        const float sy  = fmaxf(syv, SIGMA_MIN_F);
        const float sw  = fminf(fmaxf(swv, -SIGMA_MIN_F), SIGMA_MIN_F);
        const float d1 = rel0 - mu.x;
        const float d2 = rel1 - mu.y;
        const float z1 = d1 / sx;
        const float z2 = (d2 - sw * z1) / sy;
        const float av  = act ? (lv_r - 0.5f * (z1 * z1 + z2 * z2) - LOG_2PI_F - __logf(sx * sy))
                              : -INFINITY;
        const float lvm = act ? lv_r : -INFINITY;

        // ---- two LSEs via width-32 xor trees ----
        float m1 = av, m2 = lvm;
        #pragma unroll
        for (int off = 16; off > 0; off >>= 1) {
            m1 = fmaxf(m1, __shfl_xor(m1, off, 32));
            m2 = fmaxf(m2, __shfl_xor(m2, off, 32));
        }
        float e1 = __expf(av - m1);     // av=-inf -> 0
        float e2 = __expf(lvm - m2);
        #pragma unroll
        for (int off = 16; off > 0; off >>= 1) {
            e1 += __shfl_xor(e1, off, 32);
            e2 += __shfl_xor(e2, off, 32);
        }
        const float logp = (m1 + __logf(e1)) - (m2 + __logf(e2)); // same in all 32 lanes

        // ---- pen loss (redundant across the half-wave, scaled by 1/32) ----
        const float mq = fmaxf(fmaxf(q0, q1), q2);
        const float lseq = mq + __logf(__expf(q0 - mq) + __expf(q1 - mq) + __expf(q2 - mq));
        const float penv = pt0 * (q0 - lseq) + pt1 * (q1 - lseq) + pt2 * (q2 - lseq);

        accp += logp * (1.0f / 32.0f);
        acce += penv * (1.0f / 32.0f);
    }

    // ---- block reduction: wave shuffle + LDS across 8 waves ----
    const int lane = threadIdx.x & 63;
    const int wid  = threadIdx.x >> 6;
    #pragma unroll
    for (int off = 32; off > 0; off >>= 1) {
        accp += __shfl_down(accp, off, 64);
        acce += __shfl_down(acce, off, 64);
    }
    __shared__ float s_pos[8], s_pen[8];
    if (lane == 0) { s_pos[wid] = accp; s_pen[wid] = acce; }
    __syncthreads();
    if (threadIdx.x == 0) {
        float P = 0.0f, E = 0.0f;
        #pragma unroll
        for (int w = 0; w < 8; ++w) { P += s_pos[w]; E += s_pen[w]; }
        partials[blockIdx.x * 2 + 0] = P;
        partials[blockIdx.x * 2 + 1] = E;
    }
}

__global__ __launch_bounds__(256) void sketch_reduce_kernel(
    const float* __restrict__ partials, float* __restrict__ out)
{
    float tp = 0.0f, te = 0.0f;
    for (int i = threadIdx.x; i < NBLK; i += 256) {
        tp += partials[2 * i + 0];
        te += partials[2 * i + 1];
    }
    #pragma unroll
    for (int off = 32; off > 0; off >>= 1) {
        tp += __shfl_down(tp, off, 64);
        te += __shfl_down(te, off, 64);
    }
    __shared__ float sp[4], se[4];
    const int lane = threadIdx.x & 63;
    const int wid  = threadIdx.x >> 6;
    if (lane == 0) { sp[wid] = tp; se[wid] = te; }
    __syncthreads();
    if (threadIdx.x == 0) {
        const float P = sp[0] + sp[1] + sp[2] + sp[3];
        const float E = se[0] + se[1] + se[2] + se[3];
        out[0] = -P / (float)NROWS;
        out[1] = -E / (float)NROWS;
    }
}

extern "C" void kernel_launch(void* const* d_in, const int* in_sizes, int n_in,
                              void* d_out, int out_size, void* d_ws, size_t ws_size,
                              hipStream_t stream) {
    const float* xs     = (const float*)d_in[0];
    const float* logits = (const float*)d_in[1];
    const float* mus    = (const float*)d_in[2];
    const float* sx     = (const float*)d_in[3];
    const float* sy     = (const float*)d_in[4];
    const float* sxy    = (const float*)d_in[5];
    const float* pen    = (const float*)d_in[6];
    float* out = (float*)d_out;
    float* partials = (float*)d_ws;          // NBLK * 2 floats = 16 KiB

    sketch_loss_kernel<<<NBLK, BLOCK, 0, stream>>>(xs, logits, mus, sx, sy, sxy, pen, partials);
    sketch_reduce_kernel<<<1, 256, 0, stream>>>(partials, out);
}

// Round 4
// 48.298 us; speedup vs baseline: 1.8522x; 1.8522x over previous
//
#include <hip/hip_runtime.h>
#include <math.h>

static constexpr int S_LEN = 2048;
static constexpr int KMIX  = 20;
static constexpr int NROWS = 256 * 2048;             // B*S
static constexpr int BLOCK = 256;                    // 2 lanes per row -> 128 rows/block
static constexpr int ROWS_PER_BLOCK = BLOCK / 2;
static constexpr int NBLK  = NROWS / ROWS_PER_BLOCK; // 4096
static constexpr float SIGMA_MIN_F = 0.01f;
static constexpr float LOG_2PI_F   = 1.8378770664093453f;
static constexpr float TMAX_LOG_F  = 9.2103403719761836f;  // log(1/SIGMA_MIN^2) = log(1e4)

__global__ __launch_bounds__(BLOCK) void sketch_loss_kernel(
    const float* __restrict__ xs,
    const float* __restrict__ logits,
    const float* __restrict__ mus,
    const float* __restrict__ sxp,
    const float* __restrict__ syp,
    const float* __restrict__ sxyp,
    const float* __restrict__ pen,
    float* __restrict__ partials)
{
    const int tid = blockIdx.x * BLOCK + threadIdx.x;
    const int r   = tid >> 1;          // row
    const int h   = tid & 1;           // K-half: components h*10 .. h*10+9

    // ---------------- hoisted loads: issue EVERYTHING up front ----------------
    const float2* lg2  = (const float2*)(logits + (size_t)r * KMIX + h * 10);
    const float2* sx2  = (const float2*)(sxp    + (size_t)r * KMIX + h * 10);
    const float2* sy2  = (const float2*)(syp    + (size_t)r * KMIX + h * 10);
    const float2* sw2  = (const float2*)(sxyp   + (size_t)r * KMIX + h * 10);
    const float4* mu4  = (const float4*)(mus    + (size_t)r * (2 * KMIX) + h * 20);

    float2 L[5], X[5], Y[5], W[5];
    float4 M[5];
    #pragma unroll
    for (int c = 0; c < 5; ++c) L[c] = lg2[c];
    #pragma unroll
    for (int c = 0; c < 5; ++c) X[c] = sx2[c];
    #pragma unroll
    for (int c = 0; c < 5; ++c) Y[c] = sy2[c];
    #pragma unroll
    for (int c = 0; c < 5; ++c) W[c] = sw2[c];
    #pragma unroll
    for (int c = 0; c < 5; ++c) M[c] = mu4[c];

    const float* xr = xs + (size_t)r * 5;
    const float x0 = xr[0], x1 = xr[1];
    const float pt0 = xr[2], pt1 = xr[3], pt2 = xr[4];
    const int s = r & (S_LEN - 1);
    const int rn = (s == S_LEN - 1) ? (r - (S_LEN - 1)) : (r + 1);
    const float* xnr = xs + (size_t)rn * 5;
    const float xn0 = xnr[0], xn1 = xnr[1];

    const float* pr = pen + (size_t)r * 3;
    const float q0 = pr[0], q1 = pr[1], q2 = pr[2];

    // pin: loads stay clustered above, compute below
    __builtin_amdgcn_sched_barrier(0);

    // ---------------- compute ----------------
    const float rel0 = xn0 - x0;
    const float rel1 = xn1 - x1;

    float u[10], t[10], lv[10];
    #pragma unroll
    for (int c = 0; c < 10; ++c) {
        const float l_  = (c & 1) ? L[c >> 1].y : L[c >> 1].x;
        const float sxv = (c & 1) ? X[c >> 1].y : X[c >> 1].x;
        const float syv = (c & 1) ? Y[c >> 1].y : Y[c >> 1].x;
        const float swv = (c & 1) ? W[c >> 1].y : W[c >> 1].x;
        const float m0  = (c & 1) ? M[c >> 1].z : M[c >> 1].x;
        const float m1  = (c & 1) ? M[c >> 1].w : M[c >> 1].y;

        const float sx = fmaxf(sxv, SIGMA_MIN_F);
        const float sy = fmaxf(syv, SIGMA_MIN_F);
        const float sw = fminf(fmaxf(swv, -SIGMA_MIN_F), SIGMA_MIN_F);
        const float tc = __builtin_amdgcn_rcpf(sx * sy);   // 1/(sx*sy), single v_rcp
        const float d1 = rel0 - m0;
        const float d2 = rel1 - m1;
        const float z1 = d1 * sy * tc;                      // d1/sx
        const float z2 = (d2 - sw * z1) * sx * tc;          // (d2-sw*z1)/sy
        lv[c] = l_;
        t[c]  = tc;
        u[c]  = l_ - 0.5f * (z1 * z1 + z2 * z2) - LOG_2PI_F;
    }

    // local maxima over private components
    float mu_ = u[0], ml_ = lv[0];
    #pragma unroll
    for (int c = 1; c < 10; ++c) { mu_ = fmaxf(mu_, u[c]); ml_ = fmaxf(ml_, lv[c]); }
    // combine across the lane pair (partner = lane^1)
    mu_ = fmaxf(mu_, __shfl_xor(mu_, 1, 64));
    ml_ = fmaxf(ml_, __shfl_xor(ml_, 1, 64));
    const float mhat = mu_ + TMAX_LOG_F;   // safe shift: u + log(t) <= mu_ + log(1e4)

    float s1 = 0.0f, s2 = 0.0f;
    #pragma unroll
    for (int c = 0; c < 10; ++c) {
        s1 += t[c] * __expf(u[c] - mhat);
        s2 += __expf(lv[c] - ml_);
    }
    s1 += __shfl_xor(s1, 1, 64);
    s2 += __shfl_xor(s2, 1, 64);

    const float logp = (mhat + __logf(s1)) - (ml_ + __logf(s2));  // same in both lanes

    // ---- pen loss (redundant across the pair, scaled by 1/2) ----
    const float mq = fmaxf(fmaxf(q0, q1), q2);
    const float lseq = mq + __logf(__expf(q0 - mq) + __expf(q1 - mq) + __expf(q2 - mq));
    const float penv = pt0 * (q0 - lseq) + pt1 * (q1 - lseq) + pt2 * (q2 - lseq);

    float accp = logp * 0.5f;
    float acce = penv * 0.5f;

    // ---- block reduction (wave shuffle + LDS across 4 waves) ----
    const int lane = threadIdx.x & 63;
    const int wid  = threadIdx.x >> 6;
    #pragma unroll
    for (int off = 32; off > 0; off >>= 1) {
        accp += __shfl_down(accp, off, 64);
        acce += __shfl_down(acce, off, 64);
    }
    __shared__ float s_pos[4], s_pen[4];
    if (lane == 0) { s_pos[wid] = accp; s_pen[wid] = acce; }
    __syncthreads();
    if (threadIdx.x == 0) {
        partials[blockIdx.x * 2 + 0] = s_pos[0] + s_pos[1] + s_pos[2] + s_pos[3];
        partials[blockIdx.x * 2 + 1] = s_pen[0] + s_pen[1] + s_pen[2] + s_pen[3];
    }
}

__global__ __launch_bounds__(256) void sketch_reduce_kernel(
    const float* __restrict__ partials, float* __restrict__ out)
{
    float tp = 0.0f, te = 0.0f;
    for (int i = threadIdx.x; i < NBLK; i += 256) {
        tp += partials[2 * i + 0];
        te += partials[2 * i + 1];
    }
    #pragma unroll
    for (int off = 32; off > 0; off >>= 1) {
        tp += __shfl_down(tp, off, 64);
        te += __shfl_down(te, off, 64);
    }
    __shared__ float sp[4], se[4];
    const int lane = threadIdx.x & 63;
    const int wid  = threadIdx.x >> 6;
    if (lane == 0) { sp[wid] = tp; se[wid] = te; }
    __syncthreads();
    if (threadIdx.x == 0) {
        const float P = sp[0] + sp[1] + sp[2] + sp[3];
        const float E = se[0] + se[1] + se[2] + se[3];
        out[0] = -P / (float)NROWS;
        out[1] = -E / (float)NROWS;
    }
}

extern "C" void kernel_launch(void* const* d_in, const int* in_sizes, int n_in,
                              void* d_out, int out_size, void* d_ws, size_t ws_size,
                              hipStream_t stream) {
    const float* xs     = (const float*)d_in[0];
    const float* logits = (const float*)d_in[1];
    const float* mus    = (const float*)d_in[2];
    const float* sx     = (const float*)d_in[3];
    const float* sy     = (const float*)d_in[4];
    const float* sxy    = (const float*)d_in[5];
    const float* pen    = (const float*)d_in[6];
    float* out = (float*)d_out;
    float* partials = (float*)d_ws;          // NBLK * 2 floats = 32 KiB

    sketch_loss_kernel<<<NBLK, BLOCK, 0, stream>>>(xs, logits, mus, sx, sy, sxy, pen, partials);
    sketch_reduce_kernel<<<1, 256, 0, stream>>>(partials, out);
}